// Round 9
// baseline (438.040 us; speedup 1.0000x reference)
//
#include <hip/hip_runtime.h>

// SkipGram negative-sampling loss on MI355X — round 9.
// Miss-path is saturated (R4-R8: 287MB TCC-fetch @ 3.4 TB/s regardless of
// structure). Attack miss BYTES via vocab-sliced partitioning: block's
// slice = blockIdx.x & 7; block computes only dots whose label lies in
// [slice*12500, slice*12500+12500). Every element is visited by 8 blocks
// (one per slice) -> each dot computed exactly once, correct under any
// dispatch mapping. Under round-robin bid%8->XCD, each XCD's L2 touches
// only a 6.4MB slice of output_emb instead of all 51MB.

#define VOCAB    100000
#define EMB      128
#define B_TOT    16384
#define W_POS    10
#define K_NEG    64
#define N_LAB    (W_POS + K_NEG)   // 74
#define NCHUNK   19                // ceil(74/4)
#define NSLICE   8
#define SLICE_SZ (VOCAB / NSLICE)  // 12500, exact

__device__ __forceinline__ float logsig(float x) {
    // log_sigmoid(x) = min(x,0) - log1p(exp(-|x|)); hw exp/log only.
    const float e = __expf(-fabsf(x));
    return fminf(x, 0.0f) - 0.69314718056f * __log2f(1.0f + e);
}

__global__ __launch_bounds__(256) void skipgram_kernel(
    const int*   __restrict__ input,       // [B]
    const int*   __restrict__ pos_labels,  // [B, W_POS]
    const int*   __restrict__ neg_labels,  // [B, K_NEG]
    const float* __restrict__ input_emb,   // [VOCAB, EMB]
    const float* __restrict__ output_emb,  // [VOCAB, EMB]
    float*       __restrict__ out)         // [1]
{
    const int lane  = threadIdx.x & 63;
    const int gl    = lane & 15;   // lane within 16-lane group
    const int grp   = lane >> 4;   // which label of each 4-label chunk
    const int w     = threadIdx.x >> 6;          // wave in block
    const int slice = blockIdx.x & (NSLICE - 1); // == XCD if round-robin
    const int e     = ((int)blockIdx.x >> 3) * 4 + w;  // element
    const int lo    = slice * SLICE_SZ;

    const int* pl = pos_labels + e * W_POS;
    const int* nl = neg_labels + e * K_NEG;

    // ---- all 19 index loads up front; slice-membership predicate ----
    int  idx[NCHUNK];
    bool act[NCHUNK];
    #pragma unroll
    for (int t = 0; t < NCHUNK; ++t) {
        const int j = 4 * t + grp;
        const int r = (j < W_POS) ? pl[j] : ((j < N_LAB) ? nl[j - W_POS] : -1);
        idx[t] = r;
        act[t] = (unsigned)(r - lo) < (unsigned)SLICE_SZ;  // false for r=-1
    }

    // ---- center row (re-gathered once per slice-block) ----
    const int c = input[e];
    const float4* crow = (const float4*)(input_emb + (size_t)c * EMB);
    const float4 c0 = crow[gl * 2], c1 = crow[gl * 2 + 1];

    float acc = 0.0f;

    #pragma unroll
    for (int t = 0; t < NCHUNK; ++t) {
        float4 a0 = make_float4(0.f, 0.f, 0.f, 0.f);
        float4 a1 = make_float4(0.f, 0.f, 0.f, 0.f);
        // Predicated gather: out-of-slice labels issue NO memory traffic.
        if (act[t]) {
            const float4* rp = (const float4*)(output_emb + (size_t)idx[t] * EMB);
            a0 = rp[gl * 2];
            a1 = rp[gl * 2 + 1];
        }

        float p = a0.x * c0.x + a0.y * c0.y + a0.z * c0.z + a0.w * c0.w
                + a1.x * c1.x + a1.y * c1.y + a1.z * c1.z + a1.w * c1.w;

        p += __shfl_xor(p, 1);
        p += __shfl_xor(p, 2);
        p += __shfl_xor(p, 4);
        p += __shfl_xor(p, 8);

        if (gl == 0 && act[t]) acc += logsig(p);
    }

    // ---- wave reduce (group leaders) then block reduce -> 1 atomic ----
    acc += __shfl_xor(acc, 16);
    acc += __shfl_xor(acc, 32);

    __shared__ float part[4];
    if (lane == 0) part[w] = acc;
    __syncthreads();
    if (threadIdx.x == 0) {
        const float s = part[0] + part[1] + part[2] + part[3];
        atomicAdd(out, -s);
    }
}

extern "C" void kernel_launch(void* const* d_in, const int* in_sizes, int n_in,
                              void* d_out, int out_size, void* d_ws, size_t ws_size,
                              hipStream_t stream) {
    const int*   input      = (const int*)  d_in[0];
    const int*   pos_labels = (const int*)  d_in[1];
    const int*   neg_labels = (const int*)  d_in[2];
    const float* input_emb  = (const float*)d_in[3];
    const float* output_emb = (const float*)d_in[4];
    float*       out        = (float*)      d_out;

    // d_out is poisoned (0xAA) and not re-zeroed between replays.
    hipMemsetAsync(out, 0, sizeof(float), stream);

    // 32768 blocks x 256 threads: block g -> slice g&7, elements (g>>3)*4+w.
    // 8 slice-blocks per 4-element group; every dot computed exactly once.
    dim3 grid(32768), block(256);
    hipLaunchKernelGGL(skipgram_kernel, grid, block, 0, stream,
                       input, pos_labels, neg_labels, input_emb, output_emb, out);
}